// Round 6
// baseline (369.461 us; speedup 1.0000x reference)
//
#include <hip/hip_runtime.h>
#include <math.h>

#define B_ 64
#define N_ 2048
#define O_ 32
#define I_ 16
#define D_ 32
#define OD_ 1024

typedef __attribute__((ext_vector_type(8))) short bf16x8;
typedef __attribute__((ext_vector_type(4))) float f32x4;

union FragU { unsigned u[4]; uint4 v; bf16x8 f; };

// lgkm-only barrier: does not drain vmcnt (global prefetches stay in flight).
__device__ __forceinline__ void barrier_lds() {
  asm volatile("s_waitcnt lgkmcnt(0)\n\ts_barrier" ::: "memory");
}

// ---- DPP cross-lane (VALU pipe, no LDS traffic) ----
template <int CTRL>
__device__ __forceinline__ float dpp_mov_f(float x) {
  return __int_as_float(
      __builtin_amdgcn_update_dpp(0, __float_as_int(x), CTRL, 0xf, 0xf, true));
}
__device__ __forceinline__ float grp32_max(float x) {
  x = fmaxf(x, dpp_mov_f<0xb1>(x));
  x = fmaxf(x, dpp_mov_f<0x4e>(x));
  x = fmaxf(x, dpp_mov_f<0x124>(x));
  x = fmaxf(x, dpp_mov_f<0x128>(x));
  x = fmaxf(x, __shfl_xor(x, 16));
  return x;
}
__device__ __forceinline__ float grp32_sum(float x) {
  x += dpp_mov_f<0xb1>(x);
  x += dpp_mov_f<0x4e>(x);
  x += dpp_mov_f<0x124>(x);
  x += dpp_mov_f<0x128>(x);
  x += __shfl_xor(x, 16);
  return x;
}

__device__ __forceinline__ void dk_split(float f, unsigned &h, unsigned &l) {
  unsigned u = __float_as_uint(f);
  h = u & 0xffff0000u;
  float lo = f - __uint_as_float(h);
  l = __float_as_uint(lo) >> 16;
}
__device__ __forceinline__ void dk_split16(float f, unsigned short &h,
                                           unsigned short &l) {
  unsigned u = __float_as_uint(f);
  unsigned hu = u & 0xffff0000u;
  h = (unsigned short)(u >> 16);
  float lo = f - __uint_as_float(hu);
  l = (unsigned short)(__float_as_uint(lo) >> 16);
}
__device__ __forceinline__ unsigned pk(unsigned short e0, unsigned short e1) {
  return (unsigned)e0 | ((unsigned)e1 << 16);
}

// ---- prep_x: pack x -> XP only ----
// XP u4 idx = (((bg*2048+n)*2 + sel)*2 + qp)*16 + c ; b = bg*16 + c
__global__ __launch_bounds__(256) void prep_x(const float* __restrict__ x,
                                              uint4* __restrict__ XP) {
  const int tid = threadIdx.x;
  int t = blockIdx.x * 256 + tid;  // 131,072
  int c = t & 15, n = (t >> 4) & 2047, bg = t >> 15;
  const f32x4* xq = (const f32x4*)(x + ((size_t)(bg * 16 + c) * N_ + n) * I_);
  float xv[I_];
#pragma unroll
  for (int k = 0; k < 4; ++k) {
    f32x4 q4 = __builtin_nontemporal_load(xq + k);
    xv[4 * k + 0] = q4[0];
    xv[4 * k + 1] = q4[1];
    xv[4 * k + 2] = q4[2];
    xv[4 * k + 3] = q4[3];
  }
  unsigned short hh[I_], ll[I_];
#pragma unroll
  for (int i = 0; i < I_; ++i) dk_split16(xv[i], hh[i], ll[i]);
  size_t base = ((size_t)bg * N_ + n) * 4;
#pragma unroll
  for (int sel = 0; sel < 2; ++sel) {
    const unsigned short* e = sel ? ll : hh;
#pragma unroll
    for (int qp = 0; qp < 2; ++qp) {
      uint4 u;
      u.x = pk(e[qp * 8 + 0], e[qp * 8 + 1]);
      u.y = pk(e[qp * 8 + 2], e[qp * 8 + 3]);
      u.z = pk(e[qp * 8 + 4], e[qp * 8 + 5]);
      u.w = pk(e[qp * 8 + 6], e[qp * 8 + 7]);
      XP[(base + sel * 2 + qp) * 16 + c] = u;
    }
  }
}

// ---- pass1_fused v2: double-buffered wstage, no block barrier, nt-W ----
// R5's v1 was dependency-serialized (MfmaUtil 6.6%, nothing saturated): the
// single-buffer wstage made each nl's ds_write alias the pack reads, chaining
// global->wait->LDS->wait->pack->MFMA with no slack. v2: (1) wstage[2] --
// write buf[(nl+1)&1], pack buf[nl&1], statically distinct -> no alias order,
// W-load->ds_write cover = 1 full iteration; (2) XP fragments read directly
// from global (2 KB/nl slice, L1-resident after first wave) -> xps staging
// and the ONLY block barrier removed; 16 waves free-run; (3) W loads are
// nontemporal (W dead after this kernel) -> L3 reserved for WP, which the 2
// routing passes re-read. Manual 2-step unroll keeps buffer roles static.
// LDS = 128 KB, 1 block/CU (grid 256).
__global__ __launch_bounds__(1024, 4) void pass1_fused(
    const uint4* __restrict__ XP, const float* __restrict__ W,
    uint4* __restrict__ WP, float* __restrict__ partial, int NC) {
  const int tid = threadIdx.x;
  const int lane = tid & 63;
  const int w = tid >> 6;
  const int q = lane >> 4;
  const int c = lane & 15;
  const int qp = q & 1;
  const int ch = blockIdx.x;
  const int bgy = blockIdx.y;

  __shared__ float wstage[2][16][1024];  // 128 KB, per-wave 4 KB x 2 buffers

  const int n0 = ch * NC;

  f32x4 s_t[2][4];
#pragma unroll
  for (int bgl = 0; bgl < 2; ++bgl)
#pragma unroll
    for (int ct = 0; ct < 4; ++ct) s_t[bgl][ct] = (f32x4){0.f, 0.f, 0.f, 0.f};

  // wave's W source: o = 2w..2w+1 -> 1024 consecutive floats at (n*32+2w)*512
  const float* wsrc = W + (size_t)(2 * w) * 512;
  const uint4* xb0 = XP + (size_t)(bgy * 2 + 0) * 131072;
  const uint4* xb1 = XP + (size_t)(bgy * 2 + 1) * 131072;

  f32x4* wb0 = (f32x4*)wstage[0][w];
  f32x4* wb1 = (f32x4*)wstage[1][w];
  const float* wr0 = wstage[0][w];
  const float* wr1 = wstage[1][w];

  f32x4 wA[4], wB[4];
  // prologue: buf0 <- W(n0); wA <- W(n0+1)
  {
    const f32x4* g = (const f32x4*)(wsrc + (size_t)n0 * 16384);
#pragma unroll
    for (int k = 0; k < 4; ++k)
      wA[k] = __builtin_nontemporal_load(g + lane + k * 64);
#pragma unroll
    for (int k = 0; k < 4; ++k) wb0[lane + k * 64] = wA[k];
    const f32x4* g1 = (const f32x4*)(wsrc + (size_t)(n0 + 1) * 16384);
#pragma unroll
    for (int k = 0; k < 4; ++k)
      wA[k] = __builtin_nontemporal_load(g1 + lane + k * 64);
  }

#define P1_BODY(NL, WREAD, WWRITE, WRIN, WROUT)                               \
  {                                                                           \
    const int nl_ = (NL);                                                     \
    const size_t n_ = (size_t)(n0 + nl_);                                     \
    const int nn_ = (nl_ + 2 < NC) ? nl_ + 2 : NC - 1;                        \
    const f32x4* g_ = (const f32x4*)(wsrc + (size_t)(n0 + nn_) * 16384);      \
    _Pragma("unroll") for (int k = 0; k < 4; ++k)                             \
        WROUT[k] = __builtin_nontemporal_load(g_ + lane + k * 64);            \
    FragU ah0, al0, ah1, al1;                                                 \
    ah0.v = xb0[n_ * 64 + qp * 16 + c];                                       \
    al0.v = xb0[n_ * 64 + (2 + qp) * 16 + c];                                 \
    ah1.v = xb1[n_ * 64 + qp * 16 + c];                                       \
    al1.v = xb1[n_ * 64 + (2 + qp) * 16 + c];                                 \
    _Pragma("unroll") for (int k = 0; k < 4; ++k)                             \
        WWRITE[lane + k * 64] = WRIN[k];                                      \
    FragU cb[4];                                                              \
    _Pragma("unroll") for (int ct = 0; ct < 4; ++ct) {                        \
      const int ol_ = ct >> 1, dh_ = ct & 1;                                  \
      const float* base_ = WREAD + ol_ * 512 + qp * 256 + dh_ * 16 + c;       \
      unsigned short e8[8];                                                   \
      _Pragma("unroll") for (int e = 0; e < 8; ++e) {                         \
        float f_ = base_[e * 32];                                             \
        unsigned u_ = __float_as_uint(f_);                                    \
        unsigned short hi_ = (unsigned short)(u_ >> 16);                      \
        unsigned short lo_ = (unsigned short)(                                \
            __float_as_uint(f_ - __uint_as_float(u_ & 0xffff0000u)) >> 16);   \
        e8[e] = (q < 2) ? hi_ : lo_;                                          \
      }                                                                       \
      cb[ct].u[0] = pk(e8[0], e8[1]);                                         \
      cb[ct].u[1] = pk(e8[2], e8[3]);                                         \
      cb[ct].u[2] = pk(e8[4], e8[5]);                                         \
      cb[ct].u[3] = pk(e8[6], e8[7]);                                         \
    }                                                                         \
    if (bgy == 0) {                                                           \
      uint4* wpdst_ = WP + n_ * 4096 + (size_t)(2 * w) * 128 + lane;          \
      _Pragma("unroll") for (int ct = 0; ct < 4; ++ct)                        \
          wpdst_[ct * 64] = cb[ct].v;                                         \
    }                                                                         \
    _Pragma("unroll") for (int ct = 0; ct < 4; ++ct) {                        \
      s_t[0][ct] = __builtin_amdgcn_mfma_f32_16x16x32_bf16(ah0.f, cb[ct].f,   \
                                                           s_t[0][ct], 0, 0, 0); \
      s_t[0][ct] = __builtin_amdgcn_mfma_f32_16x16x32_bf16(al0.f, cb[ct].f,   \
                                                           s_t[0][ct], 0, 0, 0); \
      s_t[1][ct] = __builtin_amdgcn_mfma_f32_16x16x32_bf16(ah1.f, cb[ct].f,   \
                                                           s_t[1][ct], 0, 0, 0); \
      s_t[1][ct] = __builtin_amdgcn_mfma_f32_16x16x32_bf16(al1.f, cb[ct].f,   \
                                                           s_t[1][ct], 0, 0, 0); \
    }                                                                         \
  }

  for (int nl = 0; nl < NC; nl += 2) {
    // even: write buf1 <- wA (=W(nl+1)), pack buf0 (=W(nl)), load W(nl+2)->wB
    P1_BODY(nl, wr0, wb1, wA, wB);
    // odd: write buf0 <- wB (=W(nl+2)), pack buf1 (=W(nl+1)), load ->wA
    P1_BODY(nl + 1, wr1, wb0, wB, wA);
  }
#undef P1_BODY

  const float scale = 1.f / 32.f;
#pragma unroll
  for (int bgl = 0; bgl < 2; ++bgl)
#pragma unroll
    for (int ct = 0; ct < 4; ++ct) {
      int odc = (2 * w + (ct >> 1)) * 32 + (ct & 1) * 16 + c;
#pragma unroll
      for (int r = 0; r < 4; ++r) {
        partial[((size_t)ch * B_ + bgy * 32 + bgl * 16 + q * 4 + r) * OD_ + odc] =
            s_t[bgl][ct][r] * scale;
      }
    }
}

// ---- fused routing pass v9: v7 structure + TRANSPOSED logit MFMA ----
// (unchanged; reads WP written by pass1_fused)
template <int UNIFORM>
__global__ __launch_bounds__(1024, 4) void mfma_pass6(
    const uint4* __restrict__ XP, const uint4* __restrict__ WP,
    const float* __restrict__ v, float* __restrict__ partial, int NC) {
  const int tid = threadIdx.x;
  const int lane = tid & 63;
  const int w = tid >> 6;
  const int q = lane >> 4;
  const int c = lane & 15;
  const int qp = q & 1;
  const int ch = blockIdx.x;
  const int bgy = blockIdx.y;  // b in [bgy*32, bgy*32+32)

  __shared__ uint4 xps[2][16][4][16];  // [bgl][nl][rec][c] = 32 KB
  __shared__ float ls_l[32 * 33];      // logits [o][b] pad 33
  __shared__ float ls_c2[32 * 33];     // c      [o][b] pad 33

  const int n0 = ch * NC;

  {
    uint4* xf = (uint4*)xps;
    const int total = 2 * NC * 64;
    for (int l = tid; l < total; l += 1024) {
      int bgl = l / (NC * 64);
      int rest = l - bgl * (NC * 64);  // nl*64 + rec*16 + c
      xf[bgl * 1024 + rest] =
          XP[(size_t)(bgy * 2 + bgl) * 131072 + (size_t)n0 * 64 + rest];
    }
  }

  f32x4 s_t[2][4];
#pragma unroll
  for (int bgl = 0; bgl < 2; ++bgl)
#pragma unroll
    for (int ct = 0; ct < 4; ++ct) s_t[bgl][ct] = (f32x4){0.f, 0.f, 0.f, 0.f};

  // hoisted v fragments, indexed for the TRANSPOSED u: b=col=c, d=q*4+r
  float vreg[2][4][4];
  if (!UNIFORM) {
#pragma unroll
    for (int bgl = 0; bgl < 2; ++bgl)
#pragma unroll
      for (int ct = 0; ct < 4; ++ct) {
        const float4 vv = *(const float4*)&v[(size_t)(bgy * 32 + bgl * 16 + c) * OD_ +
                                             (2 * w + (ct >> 1)) * 32 +
                                             (ct & 1) * 16 + q * 4];
        vreg[bgl][ct][0] = vv.x;
        vreg[bgl][ct][1] = vv.y;
        vreg[bgl][ct][2] = vv.z;
        vreg[bgl][ct][3] = vv.w;
      }
  }

  barrier_lds();  // xps ready

  const uint4* wbase = WP + (size_t)(2 * w) * 128 + lane;

  FragU cb[4];
#pragma unroll
  for (int ct = 0; ct < 4; ++ct)
    cb[ct].v = wbase[(size_t)n0 * 4096 + ct * 64];

  if (UNIFORM) {
    for (int nl = 0; nl < NC; ++nl) {
      const size_t n = (size_t)(n0 + nl);
      const size_t np = (nl + 1 < NC) ? n + 1 : n;
      FragU cbn[4];
#pragma unroll
      for (int ct = 0; ct < 4; ++ct) cbn[ct].v = wbase[np * 4096 + ct * 64];
#pragma unroll
      for (int bgl = 0; bgl < 2; ++bgl) {
        FragU ah, al;
        ah.v = xps[bgl][nl][qp][c];
        al.v = xps[bgl][nl][2 + qp][c];
#pragma unroll
        for (int ct = 0; ct < 4; ++ct) {
          s_t[bgl][ct] = __builtin_amdgcn_mfma_f32_16x16x32_bf16(
              ah.f, cb[ct].f, s_t[bgl][ct], 0, 0, 0);
          s_t[bgl][ct] = __builtin_amdgcn_mfma_f32_16x16x32_bf16(
              al.f, cb[ct].f, s_t[bgl][ct], 0, 0, 0);
        }
      }
#pragma unroll
      for (int ct = 0; ct < 4; ++ct) cb[ct] = cbn[ct];
    }
  } else {
    for (int nl = 0; nl < NC; ++nl) {
      const size_t n = (size_t)(n0 + nl);
      const size_t np = (nl + 1 < NC) ? n + 1 : n;

      // ---- phase 1 (transposed): uT[d][b] -> logits ----
#pragma unroll
      for (int bgl = 0; bgl < 2; ++bgl) {
        FragU ah, al;
        ah.v = xps[bgl][nl][qp][c];
        al.v = xps[bgl][nl][2 + qp][c];
        float lgol[2] = {0.f, 0.f};
#pragma unroll
        for (int ct = 0; ct < 4; ++ct) {
          f32x4 accT = (f32x4){0.f, 0.f, 0.f, 0.f};
          accT = __builtin_amdgcn_mfma_f32_16x16x32_bf16(cb[ct].f, ah.f, accT, 0, 0, 0);
          f32x4 uT = __builtin_amdgcn_mfma_f32_16x16x32_bf16(cb[ct].f, al.f, accT, 0, 0, 0);
          const int ol = ct >> 1;
#pragma unroll
          for (int r = 0; r < 4; ++r)
            lgol[ol] = fmaf(uT[r], vreg[bgl][ct][r], lgol[ol]);
        }
#pragma unroll
        for (int ol = 0; ol < 2; ++ol) {
          float t = lgol[ol];
          t += __shfl_xor(t, 16);
          t += __shfl_xor(t, 32);
          if (q == 0) ls_l[(2 * w + ol) * 33 + bgl * 16 + c] = t;
        }
      }
      FragU cbn[4];
#pragma unroll
      for (int ct = 0; ct < 4; ++ct) cbn[ct].v = wbase[np * 4096 + ct * 64];

      barrier_lds();
      {
        const int idx = (tid & 31) * 33 + (tid >> 5);
        float l = ls_l[idx];
        float mx = grp32_max(l);
        float e = __expf(l - mx);
        float sm = grp32_sum(e);
        ls_c2[idx] = e / sm;
      }
      barrier_lds();
      // ---- phase 3 (normal orientation) ----
#pragma unroll
      for (int bgl = 0; bgl < 2; ++bgl) {
        FragU ah, al;
        ah.v = xps[bgl][nl][qp][c];
        al.v = xps[bgl][nl][2 + qp][c];
#pragma unroll
        for (int ct = 0; ct < 4; ++ct) {
          f32x4 acc = (f32x4){0.f, 0.f, 0.f, 0.f};
          acc = __builtin_amdgcn_mfma_f32_16x16x32_bf16(ah.f, cb[ct].f, acc, 0, 0, 0);
          f32x4 u = __builtin_amdgcn_mfma_f32_16x16x32_bf16(al.f, cb[ct].f, acc, 0, 0, 0);
          const int o = 2 * w + (ct >> 1);
#pragma unroll
          for (int r = 0; r < 4; ++r) {
            float cc = ls_c2[o * 33 + bgl * 16 + q * 4 + r];
            s_t[bgl][ct][r] = fmaf(cc, u[r], s_t[bgl][ct][r]);
          }
        }
      }
#pragma unroll
      for (int ct = 0; ct < 4; ++ct) cb[ct] = cbn[ct];
    }
  }

  const float scale = UNIFORM ? (1.f / 32.f) : 1.f;
#pragma unroll
  for (int bgl = 0; bgl < 2; ++bgl)
#pragma unroll
    for (int ct = 0; ct < 4; ++ct) {
      int odc = (2 * w + (ct >> 1)) * 32 + (ct & 1) * 16 + c;
#pragma unroll
      for (int r = 0; r < 4; ++r) {
        partial[((size_t)ch * B_ + bgy * 32 + bgl * 16 + q * 4 + r) * OD_ + odc] =
            s_t[bgl][ct][r] * scale;
      }
    }
}

// ---- fallback (round-2 path, used only if ws too small for WP/XP) ----
template <int UNIFORM>
__global__ __launch_bounds__(512, 4) void mfma_pass_fb(
    const float* __restrict__ x, const float* __restrict__ W,
    const float* __restrict__ v, float* __restrict__ partial, int NC) {
  const int tid = threadIdx.x;
  const int lane = tid & 63;
  const int cg = tid >> 6;
  const int q = lane >> 4;
  const int c = lane & 15;
  const int ch = blockIdx.x;
  const int bg = blockIdx.y;

  __shared__ float ls_logit[16 * O_];
  __shared__ float ls_c[16 * O_];

  f32x4 s_t[8];
#pragma unroll
  for (int ct = 0; ct < 8; ++ct) s_t[ct] = (f32x4){0.f, 0.f, 0.f, 0.f};

  const int n0 = ch * NC;
  const int ih = (q & 1) * 8;
  const float* xrow = x + ((size_t)(bg * 16 + c) * N_) * I_ + ih;

  for (int nl = 0; nl < NC; ++nl) {
    const int n = n0 + nl;
    const float* xp = xrow + (size_t)n * I_;
    float4 xv0 = *(const float4*)xp;
    float4 xv1 = *(const float4*)(xp + 4);
    float xv[8] = {xv0.x, xv0.y, xv0.z, xv0.w, xv1.x, xv1.y, xv1.z, xv1.w};
    FragU a1;
#pragma unroll
    for (int p = 0; p < 4; ++p) {
      unsigned h0, l0, h1, l1;
      dk_split(xv[2 * p], h0, l0);
      dk_split(xv[2 * p + 1], h1, l1);
      a1.u[p] = (q < 2) ? ((h0 >> 16) | h1) : (l0 | (l1 << 16));
    }
    f32x4 u_t[8];
#pragma unroll
    for (int ct = 0; ct < 8; ++ct) {
      const int o = cg * 4 + (ct >> 1);
      const int d = (ct & 1) * 16 + c;
      const float* wp = W + (((size_t)n * O_ + o) * I_ + ih) * D_ + d;
      FragU b1, b2;
#pragma unroll
      for (int p = 0; p < 4; ++p) {
        unsigned h0, l0, h1, l1;
        dk_split(wp[(2 * p) * D_], h0, l0);
        dk_split(wp[(2 * p + 1) * D_], h1, l1);
        b1.u[p] = (h0 >> 16) | h1;
        b2.u[p] = l0 | (l1 << 16);
      }
      if (UNIFORM) {
        s_t[ct] = __builtin_amdgcn_mfma_f32_16x16x32_bf16(a1.f, b1.f, s_t[ct], 0, 0, 0);
        s_t[ct] = __builtin_amdgcn_mfma_f32_16x16x32_bf16(a1.f, b2.f, s_t[ct], 0, 0, 0);
      } else {
        f32x4 acc = (f32x4){0.f, 0.f, 0.f, 0.f};
        acc = __builtin_amdgcn_mfma_f32_16x16x32_bf16(a1.f, b1.f, acc, 0, 0, 0);
        u_t[ct] = __builtin_amdgcn_mfma_f32_16x16x32_bf16(a1.f, b2.f, acc, 0, 0, 0);
      }
    }
    if (!UNIFORM) {
#pragma unroll
      for (int ol = 0; ol < 4; ++ol) {
        float lg[4] = {0.f, 0.f, 0.f, 0.f};
#pragma unroll
        for (int hf = 0; hf < 2; ++hf) {
          int ct = ol * 2 + hf;
          int odc = cg * 128 + ct * 16 + c;
#pragma unroll
          for (int r = 0; r < 4; ++r)
            lg[r] = fmaf(u_t[ct][r], v[(size_t)(bg * 16 + q * 4 + r) * OD_ + odc], lg[r]);
        }
#pragma unroll
        for (int r = 0; r < 4; ++r) {
#pragma unroll
          for (int m = 1; m < 16; m <<= 1) lg[r] += __shfl_xor(lg[r], m);
        }
        if (c == 0) {
#pragma unroll
          for (int r = 0; r < 4; ++r)
            ls_logit[(q * 4 + r) * O_ + cg * 4 + ol] = lg[r];
        }
      }
      __syncthreads();
      {
        int b_l = tid >> 5, o = tid & 31;
        float l = ls_logit[b_l * O_ + o];
        float mx = l;
#pragma unroll
        for (int m = 16; m >= 1; m >>= 1) mx = fmaxf(mx, __shfl_xor(mx, m));
        float e = __expf(l - mx);
        float sm = e;
#pragma unroll
        for (int m = 16; m >= 1; m >>= 1) sm += __shfl_xor(sm, m);
        ls_c[b_l * O_ + o] = e / sm;
      }
      __syncthreads();
#pragma unroll
      for (int ol = 0; ol < 4; ++ol) {
        int o = cg * 4 + ol;
        float cc[4];
#pragma unroll
        for (int r = 0; r < 4; ++r) cc[r] = ls_c[(q * 4 + r) * O_ + o];
#pragma unroll
        for (int hf = 0; hf < 2; ++hf) {
          int ct = ol * 2 + hf;
#pragma unroll
          for (int r = 0; r < 4; ++r)
            s_t[ct][r] = fmaf(cc[r], u_t[ct][r], s_t[ct][r]);
        }
      }
    }
  }

  const float scale = UNIFORM ? (1.f / 32.f) : 1.f;
#pragma unroll
  for (int ct = 0; ct < 8; ++ct) {
#pragma unroll
    for (int r = 0; r < 4; ++r) {
      partial[((size_t)ch * B_ + bg * 16 + q * 4 + r) * OD_ + cg * 128 + ct * 16 + c] =
          s_t[ct][r] * scale;
    }
  }
}

// ---- fused reduce: sum all chunks + squash + optional prev, one kernel ----
__global__ __launch_bounds__(256) void reduce_fused(
    const float4* __restrict__ part, int cq4, const float4* __restrict__ prev,
    float4* __restrict__ out) {
  __shared__ float4 accs[4][64];
  const int lane = threadIdx.x & 63;
  const int cg = threadIdx.x >> 6;
  const int g4 = blockIdx.x * 64 + lane;  // 256*64 = 16384 outputs
  float4 s = make_float4(0.f, 0.f, 0.f, 0.f);
  const int c0 = cg * cq4;
  for (int i = 0; i < cq4; ++i) {
    float4 p = part[(size_t)(c0 + i) * 16384 + g4];
    s.x += p.x; s.y += p.y; s.z += p.z; s.w += p.w;
  }
  accs[cg][lane] = s;
  __syncthreads();
  if (cg == 0) {
    float4 a1 = accs[1][lane], a2 = accs[2][lane], a3 = accs[3][lane];
    s.x += a1.x + a2.x + a3.x;
    s.y += a1.y + a2.y + a3.y;
    s.z += a1.z + a2.z + a3.z;
    s.w += a1.w + a2.w + a3.w;
    float sq = s.x * s.x + s.y * s.y + s.z * s.z + s.w * s.w;
#pragma unroll
    for (int m = 4; m >= 1; m >>= 1) sq += __shfl_xor(sq, m, 8);
    float scale = sq / ((1.f + sq) * (sqrtf(sq) + 1e-6f));
    float4 r = make_float4(s.x * scale, s.y * scale, s.z * scale, s.w * scale);
    if (prev) {
      float4 p = prev[g4];
      r.x += p.x; r.y += p.y; r.z += p.z; r.w += p.w;
    }
    out[g4] = r;
  }
}

// single-stage reduce (fallback path)
__global__ __launch_bounds__(256) void reduce_squash(
    const float4* __restrict__ part, int chunks,
    const float4* __restrict__ prev, float4* __restrict__ out) {
  int g4 = blockIdx.x * 256 + threadIdx.x;
  float4 s = make_float4(0.f, 0.f, 0.f, 0.f);
#pragma unroll 4
  for (int ch = 0; ch < chunks; ++ch) {
    float4 p = part[(size_t)ch * 16384 + g4];
    s.x += p.x; s.y += p.y; s.z += p.z; s.w += p.w;
  }
  float sq = s.x * s.x + s.y * s.y + s.z * s.z + s.w * s.w;
#pragma unroll
  for (int m = 4; m >= 1; m >>= 1) sq += __shfl_xor(sq, m, 8);
  float scale = sq / ((1.f + sq) * (sqrtf(sq) + 1e-6f));
  float4 r = make_float4(s.x * scale, s.y * scale, s.z * scale, s.w * scale);
  if (prev) {
    float4 p = prev[g4];
    r.x += p.x; r.y += p.y; r.z += p.z; r.w += p.w;
  }
  out[g4] = r;
}

extern "C" void kernel_launch(void* const* d_in, const int* in_sizes, int n_in,
                              void* d_out, int out_size, void* d_ws,
                              size_t ws_size, hipStream_t stream) {
  const float* x = (const float*)d_in[0];
  const float* W = (const float*)d_in[1];
  float* out = (float*)d_out;

  const size_t XP_FLOATS = 4ull * 2048 * 4 * 16 * 4;       // 2,097,152
  const size_t WP_FLOATS = 2048ull * 32 * 2 * 4 * 16 * 4;  // 33,554,432

  float* v1 = (float*)d_ws;
  float* vsum = v1 + 65536;
  float* partial = vsum + 65536;

  const int chunks = 128;  // passes require NC==16
  bool packed_path =
      (131072 + (size_t)chunks * 65536 + XP_FLOATS + WP_FLOATS) * 4 <= ws_size;

  if (packed_path) {
    uint4* XP = (uint4*)(partial + (size_t)chunks * 65536);
    uint4* WP = XP + XP_FLOATS / 4;
    const int NC = N_ / chunks;  // 16
    const int cq4 = chunks / 4;  // 32
    dim3 grid(chunks, 2);

    prep_x<<<512, 256, 0, stream>>>(x, XP);

    pass1_fused<<<grid, 1024, 0, stream>>>(XP, W, WP, partial, NC);
    reduce_fused<<<256, 256, 0, stream>>>((const float4*)partial, cq4, nullptr,
                                          (float4*)v1);
    mfma_pass6<0><<<grid, 1024, 0, stream>>>(XP, WP, v1, partial, NC);
    reduce_fused<<<256, 256, 0, stream>>>((const float4*)partial, cq4,
                                          (const float4*)v1, (float4*)vsum);
    mfma_pass6<0><<<grid, 1024, 0, stream>>>(XP, WP, vsum, partial, NC);
    reduce_fused<<<256, 256, 0, stream>>>((const float4*)partial, cq4, nullptr,
                                          (float4*)out);
  } else {
    int fchunks = 128;
    while (fchunks > 1 && (131072 + (size_t)fchunks * 65536) * 4 > ws_size)
      fchunks >>= 1;
    int NC = N_ / fchunks;
    dim3 grid(fchunks, 4);

    mfma_pass_fb<1><<<grid, 512, 0, stream>>>(x, W, nullptr, partial, NC);
    reduce_squash<<<64, 256, 0, stream>>>((const float4*)partial, fchunks,
                                          nullptr, (float4*)v1);
    mfma_pass_fb<0><<<grid, 512, 0, stream>>>(x, W, v1, partial, NC);
    reduce_squash<<<64, 256, 0, stream>>>((const float4*)partial, fchunks,
                                          (const float4*)v1, (float4*)vsum);
    mfma_pass_fb<0><<<grid, 512, 0, stream>>>(x, W, vsum, partial, NC);
    reduce_squash<<<64, 256, 0, stream>>>((const float4*)partial, fchunks,
                                          nullptr, (float4*)out);
  }
}

// Round 7
// 355.364 us; speedup vs baseline: 1.0397x; 1.0397x over previous
//
#include <hip/hip_runtime.h>
#include <math.h>

#define B_ 64
#define N_ 2048
#define O_ 32
#define I_ 16
#define D_ 32
#define OD_ 1024

typedef __attribute__((ext_vector_type(8))) short bf16x8;
typedef __attribute__((ext_vector_type(4))) float f32x4;

union FragU { unsigned u[4]; uint4 v; bf16x8 f; };

// lgkm-only barrier: does not drain vmcnt (global prefetches stay in flight).
__device__ __forceinline__ void barrier_lds() {
  asm volatile("s_waitcnt lgkmcnt(0)\n\ts_barrier" ::: "memory");
}

// ---- DPP cross-lane (VALU pipe, no LDS traffic) ----
template <int CTRL>
__device__ __forceinline__ float dpp_mov_f(float x) {
  return __int_as_float(
      __builtin_amdgcn_update_dpp(0, __float_as_int(x), CTRL, 0xf, 0xf, true));
}
__device__ __forceinline__ float grp32_max(float x) {
  x = fmaxf(x, dpp_mov_f<0xb1>(x));
  x = fmaxf(x, dpp_mov_f<0x4e>(x));
  x = fmaxf(x, dpp_mov_f<0x124>(x));
  x = fmaxf(x, dpp_mov_f<0x128>(x));
  x = fmaxf(x, __shfl_xor(x, 16));
  return x;
}
__device__ __forceinline__ float grp32_sum(float x) {
  x += dpp_mov_f<0xb1>(x);
  x += dpp_mov_f<0x4e>(x);
  x += dpp_mov_f<0x124>(x);
  x += dpp_mov_f<0x128>(x);
  x += __shfl_xor(x, 16);
  return x;
}

__device__ __forceinline__ void dk_split(float f, unsigned &h, unsigned &l) {
  unsigned u = __float_as_uint(f);
  h = u & 0xffff0000u;
  float lo = f - __uint_as_float(h);
  l = __float_as_uint(lo) >> 16;
}
__device__ __forceinline__ void dk_split16(float f, unsigned short &h,
                                           unsigned short &l) {
  unsigned u = __float_as_uint(f);
  unsigned hu = u & 0xffff0000u;
  h = (unsigned short)(u >> 16);
  float lo = f - __uint_as_float(hu);
  l = (unsigned short)(__float_as_uint(lo) >> 16);
}
__device__ __forceinline__ unsigned pk(unsigned short e0, unsigned short e1) {
  return (unsigned)e0 | ((unsigned)e1 << 16);
}

// ---- merged prep (R4 version, measured-best): LDS-transpose + nt loads ----
// blocks [0,8192) pack W -> WP; [8192,8704) pack x -> XP.
// WP u4 idx = (((n*32+o)*2 + dhalf)*4 + sel*2 + qp)*16 + c   (sel0=hi, sel1=lo)
// XP u4 idx = (((bg*2048+n)*2 + sel)*2 + qp)*16 + c ; b = bg*16 + c
__global__ __launch_bounds__(256) void prep_all(const float* __restrict__ W,
                                                const float* __restrict__ x,
                                                uint4* __restrict__ WP,
                                                uint4* __restrict__ XP) {
  __shared__ float tile[8 * 512];  // 16 KB; 8 blocks/CU still fits
  const int tid = threadIdx.x;
  if (blockIdx.x < 8192) {
    const int pair0 = blockIdx.x * 8;  // (n*32+o) linear pair index
    const f32x4* gsrc = (const f32x4*)(W + (size_t)pair0 * 512);
    f32x4* lds4 = (f32x4*)tile;
#pragma unroll
    for (int k = 0; k < 4; ++k)
      lds4[tid + k * 256] = __builtin_nontemporal_load(gsrc + tid + k * 256);
    __syncthreads();
    const int p = tid >> 5;        // which pair within block
    const int d = tid & 31;
    const int pair = pair0 + p;    // == n*32 + o
    unsigned short hh[I_], ll[I_];
#pragma unroll
    for (int i = 0; i < I_; ++i)
      dk_split16(tile[p * 512 + i * 32 + d], hh[i], ll[i]);
    const int c = d & 15, dhalf = d >> 4;
    size_t base = ((size_t)pair * 2 + dhalf) * 4;
#pragma unroll
    for (int sel = 0; sel < 2; ++sel) {
      const unsigned short* e = sel ? ll : hh;
#pragma unroll
      for (int qp = 0; qp < 2; ++qp) {
        uint4 u;
        u.x = pk(e[qp * 8 + 0], e[qp * 8 + 1]);
        u.y = pk(e[qp * 8 + 2], e[qp * 8 + 3]);
        u.z = pk(e[qp * 8 + 4], e[qp * 8 + 5]);
        u.w = pk(e[qp * 8 + 6], e[qp * 8 + 7]);
        WP[(base + sel * 2 + qp) * 16 + c] = u;
      }
    }
  } else {
    int t = (blockIdx.x - 8192) * 256 + tid;  // 131,072
    int c = t & 15, n = (t >> 4) & 2047, bg = t >> 15;
    const f32x4* xq = (const f32x4*)(x + ((size_t)(bg * 16 + c) * N_ + n) * I_);
    float xv[I_];
#pragma unroll
    for (int k = 0; k < 4; ++k) {
      f32x4 q4 = __builtin_nontemporal_load(xq + k);
      xv[4 * k + 0] = q4[0];
      xv[4 * k + 1] = q4[1];
      xv[4 * k + 2] = q4[2];
      xv[4 * k + 3] = q4[3];
    }
    unsigned short hh[I_], ll[I_];
#pragma unroll
    for (int i = 0; i < I_; ++i) dk_split16(xv[i], hh[i], ll[i]);
    size_t base = ((size_t)bg * N_ + n) * 4;
#pragma unroll
    for (int sel = 0; sel < 2; ++sel) {
      const unsigned short* e = sel ? ll : hh;
#pragma unroll
      for (int qp = 0; qp < 2; ++qp) {
        uint4 u;
        u.x = pk(e[qp * 8 + 0], e[qp * 8 + 1]);
        u.y = pk(e[qp * 8 + 2], e[qp * 8 + 3]);
        u.z = pk(e[qp * 8 + 4], e[qp * 8 + 5]);
        u.w = pk(e[qp * 8 + 6], e[qp * 8 + 7]);
        XP[(base + sel * 2 + qp) * 16 + c] = u;
      }
    }
  }
}

// ---- fused routing pass v10: v9 + transposed ACCUMULATE (phase3 MFMA-free)
// Verified (R4, absmax-stable): transposed phase1's uT[r] = u[b=c][od=..+q*4+r].
// mfma(B,A)=mfma(A,B)^T with identical dot values, so phase3's recompute of u
// was redundant: keep ut in regs across softmax and accumulate s in the
// TRANSPOSED layout (s_t[bgl][ct][r] holds s[b=bgl*16+c][od=..+q*4+r]).
// Phase3: 4 broadcast LDS reads + 32 fmaf (was 8 ds_read_b128 + 16 MFMA + 32
// LDS + 32 fmaf). cb dies after phase1 -> next-nl WP load reuses cb's regs
// (no cbn). Epilogue: per-wave 16x16 transpose via LDS (reuses dead xps,
// pad 18 -> 2-way=free, no block barrier needed: all waves passed the final
// softmax barrier, after which xps is never read) so the partial write is
// bit-identical to v9's. Values bit-identical -> absmax must stay 0.00390625.
template <int UNIFORM>
__global__ __launch_bounds__(1024, 4) void mfma_pass6(
    const uint4* __restrict__ XP, const uint4* __restrict__ WP,
    const float* __restrict__ v, float* __restrict__ partial, int NC) {
  const int tid = threadIdx.x;
  const int lane = tid & 63;
  const int w = tid >> 6;
  const int q = lane >> 4;
  const int c = lane & 15;
  const int qp = q & 1;
  const int ch = blockIdx.x;
  const int bgy = blockIdx.y;  // b in [bgy*32, bgy*32+32)

  __shared__ uint4 xps[2][16][4][16];  // [bgl][nl][rec][c] = 32 KB
  __shared__ float ls_l[32 * 33];      // logits [o][b] pad 33
  __shared__ float ls_c2[32 * 33];     // c      [o][b] pad 33

  const int n0 = ch * NC;

  {
    uint4* xf = (uint4*)xps;
    const int total = 2 * NC * 64;
    for (int l = tid; l < total; l += 1024) {
      int bgl = l / (NC * 64);
      int rest = l - bgl * (NC * 64);  // nl*64 + rec*16 + c
      xf[bgl * 1024 + rest] =
          XP[(size_t)(bgy * 2 + bgl) * 131072 + (size_t)n0 * 64 + rest];
    }
  }

  f32x4 s_t[2][4];
#pragma unroll
  for (int bgl = 0; bgl < 2; ++bgl)
#pragma unroll
    for (int ct = 0; ct < 4; ++ct) s_t[bgl][ct] = (f32x4){0.f, 0.f, 0.f, 0.f};

  // hoisted v fragments, indexed for the TRANSPOSED u: b=col=c, d=q*4+r
  float vreg[2][4][4];
  if (!UNIFORM) {
#pragma unroll
    for (int bgl = 0; bgl < 2; ++bgl)
#pragma unroll
      for (int ct = 0; ct < 4; ++ct) {
        const float4 vv = *(const float4*)&v[(size_t)(bgy * 32 + bgl * 16 + c) * OD_ +
                                             (2 * w + (ct >> 1)) * 32 +
                                             (ct & 1) * 16 + q * 4];
        vreg[bgl][ct][0] = vv.x;
        vreg[bgl][ct][1] = vv.y;
        vreg[bgl][ct][2] = vv.z;
        vreg[bgl][ct][3] = vv.w;
      }
  }

  barrier_lds();  // xps ready

  const uint4* wbase = WP + (size_t)(2 * w) * 128 + lane;

  FragU cb[4];
#pragma unroll
  for (int ct = 0; ct < 4; ++ct)
    cb[ct].v = wbase[(size_t)n0 * 4096 + ct * 64];

  if (UNIFORM) {
    for (int nl = 0; nl < NC; ++nl) {
      const size_t n = (size_t)(n0 + nl);
      const size_t np = (nl + 1 < NC) ? n + 1 : n;
      FragU cbn[4];
#pragma unroll
      for (int ct = 0; ct < 4; ++ct) cbn[ct].v = wbase[np * 4096 + ct * 64];
#pragma unroll
      for (int bgl = 0; bgl < 2; ++bgl) {
        FragU ah, al;
        ah.v = xps[bgl][nl][qp][c];
        al.v = xps[bgl][nl][2 + qp][c];
#pragma unroll
        for (int ct = 0; ct < 4; ++ct) {
          s_t[bgl][ct] = __builtin_amdgcn_mfma_f32_16x16x32_bf16(
              ah.f, cb[ct].f, s_t[bgl][ct], 0, 0, 0);
          s_t[bgl][ct] = __builtin_amdgcn_mfma_f32_16x16x32_bf16(
              al.f, cb[ct].f, s_t[bgl][ct], 0, 0, 0);
        }
      }
#pragma unroll
      for (int ct = 0; ct < 4; ++ct) cb[ct] = cbn[ct];
    }
  } else {
    for (int nl = 0; nl < NC; ++nl) {
      const size_t n = (size_t)(n0 + nl);
      const size_t np = (nl + 1 < NC) ? n + 1 : n;

      // ---- phase 1 (transposed): uT -> logits; KEEP ut for phase3 ----
      f32x4 ut[2][4];
#pragma unroll
      for (int bgl = 0; bgl < 2; ++bgl) {
        FragU ah, al;
        ah.v = xps[bgl][nl][qp][c];
        al.v = xps[bgl][nl][2 + qp][c];
        float lgol[2] = {0.f, 0.f};
#pragma unroll
        for (int ct = 0; ct < 4; ++ct) {
          f32x4 accT = (f32x4){0.f, 0.f, 0.f, 0.f};
          accT = __builtin_amdgcn_mfma_f32_16x16x32_bf16(cb[ct].f, ah.f, accT, 0, 0, 0);
          ut[bgl][ct] = __builtin_amdgcn_mfma_f32_16x16x32_bf16(cb[ct].f, al.f, accT, 0, 0, 0);
          const int ol = ct >> 1;
#pragma unroll
          for (int r = 0; r < 4; ++r)
            lgol[ol] = fmaf(ut[bgl][ct][r], vreg[bgl][ct][r], lgol[ol]);
        }
#pragma unroll
        for (int ol = 0; ol < 2; ++ol) {
          float t = lgol[ol];
          t += __shfl_xor(t, 16);
          t += __shfl_xor(t, 32);
          if (q == 0) ls_l[(2 * w + ol) * 33 + bgl * 16 + c] = t;
        }
      }
      // cb is dead now (phase3 needs only ut) -> reload in place for next nl;
      // vmcnt wait lands at next nl's phase1 (cover = softmax+bars+phase3)
#pragma unroll
      for (int ct = 0; ct < 4; ++ct) cb[ct].v = wbase[np * 4096 + ct * 64];

      barrier_lds();
      {
        const int idx = (tid & 31) * 33 + (tid >> 5);
        float l = ls_l[idx];
        float mx = grp32_max(l);
        float e = __expf(l - mx);
        float sm = grp32_sum(e);
        ls_c2[idx] = e / sm;
      }
      barrier_lds();
      // ---- phase 3: transposed accumulate, NO MFMA ----
#pragma unroll
      for (int bgl = 0; bgl < 2; ++bgl)
#pragma unroll
        for (int ol = 0; ol < 2; ++ol) {
          const float cc = ls_c2[(2 * w + ol) * 33 + bgl * 16 + c];
#pragma unroll
          for (int dh = 0; dh < 2; ++dh) {
            const int ct = ol * 2 + dh;
#pragma unroll
            for (int r = 0; r < 4; ++r)
              s_t[bgl][ct][r] = fmaf(cc, ut[bgl][ct][r], s_t[bgl][ct][r]);
          }
        }
    }
  }

  if (UNIFORM) {
    const float scale = 1.f / 32.f;
#pragma unroll
    for (int bgl = 0; bgl < 2; ++bgl)
#pragma unroll
      for (int ct = 0; ct < 4; ++ct) {
        int odc = (2 * w + (ct >> 1)) * 32 + (ct & 1) * 16 + c;
#pragma unroll
        for (int r = 0; r < 4; ++r) {
          partial[((size_t)ch * B_ + bgy * 32 + bgl * 16 + q * 4 + r) * OD_ + odc] =
              s_t[bgl][ct][r] * scale;
        }
      }
  } else {
    // ---- epilogue: per-wave 16x16 transpose (sT -> s), reuse dead xps ----
    // Safe without a block barrier: every wave has passed the last softmax
    // barrier, after which no wave reads xps; each wave uses a private slot.
    float* tw = ((float*)xps) + w * 288;  // 16 x 18-padded tile (1.15 KB/wave)
#pragma unroll
    for (int bgl = 0; bgl < 2; ++bgl)
#pragma unroll
      for (int ct = 0; ct < 4; ++ct) {
        // held: s[b = bgl*16 + c][od = (2w+ol)*32 + dh*16 + q*4 + r]
#pragma unroll
        for (int r = 0; r < 4; ++r) tw[c * 18 + q * 4 + r] = s_t[bgl][ct][r];
        f32x4 so;
#pragma unroll
        for (int r = 0; r < 4; ++r) so[r] = tw[(q * 4 + r) * 18 + c];
        const int odc = (2 * w + (ct >> 1)) * 32 + (ct & 1) * 16 + c;
#pragma unroll
        for (int r = 0; r < 4; ++r) {
          partial[((size_t)ch * B_ + bgy * 32 + bgl * 16 + q * 4 + r) * OD_ + odc] =
              so[r];
        }
      }
  }
}

// ---- fallback (round-2 path, used only if ws too small for WP/XP) ----
template <int UNIFORM>
__global__ __launch_bounds__(512, 4) void mfma_pass_fb(
    const float* __restrict__ x, const float* __restrict__ W,
    const float* __restrict__ v, float* __restrict__ partial, int NC) {
  const int tid = threadIdx.x;
  const int lane = tid & 63;
  const int cg = tid >> 6;
  const int q = lane >> 4;
  const int c = lane & 15;
  const int ch = blockIdx.x;
  const int bg = blockIdx.y;

  __shared__ float ls_logit[16 * O_];
  __shared__ float ls_c[16 * O_];

  f32x4 s_t[8];
#pragma unroll
  for (int ct = 0; ct < 8; ++ct) s_t[ct] = (f32x4){0.f, 0.f, 0.f, 0.f};

  const int n0 = ch * NC;
  const int ih = (q & 1) * 8;
  const float* xrow = x + ((size_t)(bg * 16 + c) * N_) * I_ + ih;

  for (int nl = 0; nl < NC; ++nl) {
    const int n = n0 + nl;
    const float* xp = xrow + (size_t)n * I_;
    float4 xv0 = *(const float4*)xp;
    float4 xv1 = *(const float4*)(xp + 4);
    float xv[8] = {xv0.x, xv0.y, xv0.z, xv0.w, xv1.x, xv1.y, xv1.z, xv1.w};
    FragU a1;
#pragma unroll
    for (int p = 0; p < 4; ++p) {
      unsigned h0, l0, h1, l1;
      dk_split(xv[2 * p], h0, l0);
      dk_split(xv[2 * p + 1], h1, l1);
      a1.u[p] = (q < 2) ? ((h0 >> 16) | h1) : (l0 | (l1 << 16));
    }
    f32x4 u_t[8];
#pragma unroll
    for (int ct = 0; ct < 8; ++ct) {
      const int o = cg * 4 + (ct >> 1);
      const int d = (ct & 1) * 16 + c;
      const float* wp = W + (((size_t)n * O_ + o) * I_ + ih) * D_ + d;
      FragU b1, b2;
#pragma unroll
      for (int p = 0; p < 4; ++p) {
        unsigned h0, l0, h1, l1;
        dk_split(wp[(2 * p) * D_], h0, l0);
        dk_split(wp[(2 * p + 1) * D_], h1, l1);
        b1.u[p] = (h0 >> 16) | h1;
        b2.u[p] = l0 | (l1 << 16);
      }
      if (UNIFORM) {
        s_t[ct] = __builtin_amdgcn_mfma_f32_16x16x32_bf16(a1.f, b1.f, s_t[ct], 0, 0, 0);
        s_t[ct] = __builtin_amdgcn_mfma_f32_16x16x32_bf16(a1.f, b2.f, s_t[ct], 0, 0, 0);
      } else {
        f32x4 acc = (f32x4){0.f, 0.f, 0.f, 0.f};
        acc = __builtin_amdgcn_mfma_f32_16x16x32_bf16(a1.f, b1.f, acc, 0, 0, 0);
        u_t[ct] = __builtin_amdgcn_mfma_f32_16x16x32_bf16(a1.f, b2.f, acc, 0, 0, 0);
      }
    }
    if (!UNIFORM) {
#pragma unroll
      for (int ol = 0; ol < 4; ++ol) {
        float lg[4] = {0.f, 0.f, 0.f, 0.f};
#pragma unroll
        for (int hf = 0; hf < 2; ++hf) {
          int ct = ol * 2 + hf;
          int odc = cg * 128 + ct * 16 + c;
#pragma unroll
          for (int r = 0; r < 4; ++r)
            lg[r] = fmaf(u_t[ct][r], v[(size_t)(bg * 16 + q * 4 + r) * OD_ + odc], lg[r]);
        }
#pragma unroll
        for (int r = 0; r < 4; ++r) {
#pragma unroll
          for (int m = 1; m < 16; m <<= 1) lg[r] += __shfl_xor(lg[r], m);
        }
        if (c == 0) {
#pragma unroll
          for (int r = 0; r < 4; ++r)
            ls_logit[(q * 4 + r) * O_ + cg * 4 + ol] = lg[r];
        }
      }
      __syncthreads();
      {
        int b_l = tid >> 5, o = tid & 31;
        float l = ls_logit[b_l * O_ + o];
        float mx = l;
#pragma unroll
        for (int m = 16; m >= 1; m >>= 1) mx = fmaxf(mx, __shfl_xor(mx, m));
        float e = __expf(l - mx);
        float sm = e;
#pragma unroll
        for (int m = 16; m >= 1; m >>= 1) sm += __shfl_xor(sm, m);
        ls_c[b_l * O_ + o] = e / sm;
      }
      __syncthreads();
#pragma unroll
      for (int ol = 0; ol < 4; ++ol) {
        int o = cg * 4 + ol;
        float cc[4];
#pragma unroll
        for (int r = 0; r < 4; ++r) cc[r] = ls_c[(q * 4 + r) * O_ + o];
#pragma unroll
        for (int hf = 0; hf < 2; ++hf) {
          int ct = ol * 2 + hf;
#pragma unroll
          for (int r = 0; r < 4; ++r)
            s_t[ct][r] = fmaf(cc[r], u_t[ct][r], s_t[ct][r]);
        }
      }
    }
  }

  const float scale = UNIFORM ? (1.f / 32.f) : 1.f;
#pragma unroll
  for (int ct = 0; ct < 8; ++ct) {
#pragma unroll
    for (int r = 0; r < 4; ++r) {
      partial[((size_t)ch * B_ + bg * 16 + q * 4 + r) * OD_ + cg * 128 + ct * 16 + c] =
          s_t[ct][r] * scale;
    }
  }
}

// ---- fused reduce: sum all chunks + squash + optional prev, one kernel ----
__global__ __launch_bounds__(256) void reduce_fused(
    const float4* __restrict__ part, int cq4, const float4* __restrict__ prev,
    float4* __restrict__ out) {
  __shared__ float4 accs[4][64];
  const int lane = threadIdx.x & 63;
  const int cg = threadIdx.x >> 6;
  const int g4 = blockIdx.x * 64 + lane;  // 256*64 = 16384 outputs
  float4 s = make_float4(0.f, 0.f, 0.f, 0.f);
  const int c0 = cg * cq4;
  for (int i = 0; i < cq4; ++i) {
    float4 p = part[(size_t)(c0 + i) * 16384 + g4];
    s.x += p.x; s.y += p.y; s.z += p.z; s.w += p.w;
  }
  accs[cg][lane] = s;
  __syncthreads();
  if (cg == 0) {
    float4 a1 = accs[1][lane], a2 = accs[2][lane], a3 = accs[3][lane];
    s.x += a1.x + a2.x + a3.x;
    s.y += a1.y + a2.y + a3.y;
    s.z += a1.z + a2.z + a3.z;
    s.w += a1.w + a2.w + a3.w;
    float sq = s.x * s.x + s.y * s.y + s.z * s.z + s.w * s.w;
#pragma unroll
    for (int m = 4; m >= 1; m >>= 1) sq += __shfl_xor(sq, m, 8);
    float scale = sq / ((1.f + sq) * (sqrtf(sq) + 1e-6f));
    float4 r = make_float4(s.x * scale, s.y * scale, s.z * scale, s.w * scale);
    if (prev) {
      float4 p = prev[g4];
      r.x += p.x; r.y += p.y; r.z += p.z; r.w += p.w;
    }
    out[g4] = r;
  }
}

// single-stage reduce (fallback path)
__global__ __launch_bounds__(256) void reduce_squash(
    const float4* __restrict__ part, int chunks,
    const float4* __restrict__ prev, float4* __restrict__ out) {
  int g4 = blockIdx.x * 256 + threadIdx.x;
  float4 s = make_float4(0.f, 0.f, 0.f, 0.f);
#pragma unroll 4
  for (int ch = 0; ch < chunks; ++ch) {
    float4 p = part[(size_t)ch * 16384 + g4];
    s.x += p.x; s.y += p.y; s.z += p.z; s.w += p.w;
  }
  float sq = s.x * s.x + s.y * s.y + s.z * s.z + s.w * s.w;
#pragma unroll
  for (int m = 4; m >= 1; m >>= 1) sq += __shfl_xor(sq, m, 8);
  float scale = sq / ((1.f + sq) * (sqrtf(sq) + 1e-6f));
  float4 r = make_float4(s.x * scale, s.y * scale, s.z * scale, s.w * scale);
  if (prev) {
    float4 p = prev[g4];
    r.x += p.x; r.y += p.y; r.z += p.z; r.w += p.w;
  }
  out[g4] = r;
}

extern "C" void kernel_launch(void* const* d_in, const int* in_sizes, int n_in,
                              void* d_out, int out_size, void* d_ws,
                              size_t ws_size, hipStream_t stream) {
  const float* x = (const float*)d_in[0];
  const float* W = (const float*)d_in[1];
  float* out = (float*)d_out;

  const size_t XP_FLOATS = 4ull * 2048 * 4 * 16 * 4;       // 2,097,152
  const size_t WP_FLOATS = 2048ull * 32 * 2 * 4 * 16 * 4;  // 33,554,432

  float* v1 = (float*)d_ws;
  float* vsum = v1 + 65536;
  float* partial = vsum + 65536;

  const int chunks = 128;  // passes require NC==16
  bool packed_path =
      (131072 + (size_t)chunks * 65536 + XP_FLOATS + WP_FLOATS) * 4 <= ws_size;

  if (packed_path) {
    uint4* XP = (uint4*)(partial + (size_t)chunks * 65536);
    uint4* WP = XP + XP_FLOATS / 4;
    const int NC = N_ / chunks;  // 16
    const int cq4 = chunks / 4;  // 32
    dim3 grid(chunks, 2);

    prep_all<<<8704, 256, 0, stream>>>(W, x, WP, XP);

    mfma_pass6<1><<<grid, 1024, 0, stream>>>(XP, WP, nullptr, partial, NC);
    reduce_fused<<<256, 256, 0, stream>>>((const float4*)partial, cq4, nullptr,
                                          (float4*)v1);
    mfma_pass6<0><<<grid, 1024, 0, stream>>>(XP, WP, v1, partial, NC);
    reduce_fused<<<256, 256, 0, stream>>>((const float4*)partial, cq4,
                                          (const float4*)v1, (float4*)vsum);
    mfma_pass6<0><<<grid, 1024, 0, stream>>>(XP, WP, vsum, partial, NC);
    reduce_fused<<<256, 256, 0, stream>>>((const float4*)partial, cq4, nullptr,
                                          (float4*)out);
  } else {
    int fchunks = 128;
    while (fchunks > 1 && (131072 + (size_t)fchunks * 65536) * 4 > ws_size)
      fchunks >>= 1;
    int NC = N_ / fchunks;
    dim3 grid(fchunks, 4);

    mfma_pass_fb<1><<<grid, 512, 0, stream>>>(x, W, nullptr, partial, NC);
    reduce_squash<<<64, 256, 0, stream>>>((const float4*)partial, fchunks,
                                          nullptr, (float4*)v1);
    mfma_pass_fb<0><<<grid, 512, 0, stream>>>(x, W, v1, partial, NC);
    reduce_squash<<<64, 256, 0, stream>>>((const float4*)partial, fchunks,
                                          (const float4*)v1, (float4*)vsum);
    mfma_pass_fb<0><<<grid, 512, 0, stream>>>(x, W, vsum, partial, NC);
    reduce_squash<<<64, 256, 0, stream>>>((const float4*)partial, fchunks,
                                          nullptr, (float4*)out);
  }
}